// Round 12
// baseline (190.225 us; speedup 1.0000x reference)
//
#include <hip/hip_runtime.h>
#include <hip/hip_bf16.h>

// Problem constants
#define M_VIEWS 6
#define N_ROWS  2048
#define D_IN    1152
#define D_HID   128
#define D_K     64
#define TOT_ROWS (M_VIEWS * N_ROWS)   // 12288
// E is pre-scaled by sqrt((1/tau) * log2(e)) so E'.E' = (s/tau)*log2(e):
// pair-LSE softmax runs in exp2/log2 domain with no per-element muls.
#define SCALE_E 1.6986436f
#define LOG2E   1.4426950408889634f

typedef short bf16x8 __attribute__((ext_vector_type(8)));
typedef float f32x4  __attribute__((ext_vector_type(4)));

typedef __attribute__((address_space(1))) const void gvoid_t;
typedef __attribute__((address_space(3))) void svoid_t;

__device__ inline void async16(const void* g, void* l) {
    __builtin_amdgcn_global_load_lds((gvoid_t*)g, (svoid_t*)l, 16, 0, 0);
}

#if __has_builtin(__builtin_amdgcn_exp2f)
__device__ inline float fexp2(float x) { return __builtin_amdgcn_exp2f(x); }
#else
__device__ inline float fexp2(float x) { return exp2f(x); }
#endif
#if __has_builtin(__builtin_amdgcn_logf)
__device__ inline float flog2(float x) { return __builtin_amdgcn_logf(x); }
#else
__device__ inline float flog2(float x) { return log2f(x); }
#endif

// split f32 -> bf16 hi (x) + bf16 lo residual (y), returned by value
__device__ inline short2 splitf(float v) {
    __hip_bfloat16 hb = __float2bfloat16(v);
    float rem = v - __bfloat162float(hb);
    __hip_bfloat16 lb = __float2bfloat16(rem);
    short2 r;
    r.x = *reinterpret_cast<const short*>(&hb);
    r.y = *reinterpret_cast<const short*>(&lb);
    return r;
}

// ---------------------------------------------------------------------------
// Kernel 0a: split W into hi/lo bf16 in MFMA-fragment layout.
// ---------------------------------------------------------------------------
__global__ __launch_bounds__(64) void prep_w_kernel(
    const float* __restrict__ W,
    __hip_bfloat16* __restrict__ Whi, __hip_bfloat16* __restrict__ Wlo)
{
    const int s    = blockIdx.x >> 3;   // 0..35
    const int ct   = blockIdx.x & 7;    // 0..7
    const int lane = threadIdx.x;
    const int lg = lane >> 4, lr = lane & 15;
    bf16x8 hi, lo;
    #pragma unroll
    for (int i = 0; i < 8; ++i) {
        float w = W[(size_t)(s * 32 + lg * 8 + i) * D_HID + ct * 16 + lr];
        short2 hl = splitf(w);
        hi[i] = hl.x; lo[i] = hl.y;
    }
    size_t off = ((size_t)(s * 8 + ct) * 64 + lane) * 8;
    *reinterpret_cast<bf16x8*>(Whi + off) = hi;
    *reinterpret_cast<bf16x8*>(Wlo + off) = lo;
}

// ---------------------------------------------------------------------------
// Kernel 0b: U/V as MFMA B-fragments, hi/lo split.
// ---------------------------------------------------------------------------
__global__ __launch_bounds__(64) void prep_p_kernel(
    const float* __restrict__ U, const float* __restrict__ V,
    __hip_bfloat16* __restrict__ Pfhi, __hip_bfloat16* __restrict__ Pflo)
{
    const int blk = blockIdx.x;       // 0..63
    const int mat = blk >> 5, f = blk & 31;
    const float* P = mat ? V : U;
    const int lane = threadIdx.x, lg = lane >> 4, lr = lane & 15;
    bf16x8 hi, lo;
    #pragma unroll
    for (int i = 0; i < 8; ++i) {
        float w;
        if (f < 16) {
            int s = f >> 2, ct = f & 3;
            w = P[(size_t)(s * 32 + lg * 8 + i) * D_K + ct * 16 + lr] * LOG2E;
        } else {
            int g = f - 16, s2 = g >> 3, ct2 = g & 7;
            w = P[(size_t)(ct2 * 16 + lr) * D_K + s2 * 32 + lg * 8 + i];
        }
        short2 hl = splitf(w);
        hi[i] = hl.x; lo[i] = hl.y;
    }
    size_t off = ((size_t)(mat * 32 + f) * 64 + lane) * 8;
    *reinterpret_cast<bf16x8*>(Pfhi + off) = hi;
    *reinterpret_cast<bf16x8*>(Pflo + off) = lo;
}

// ---------------------------------------------------------------------------
// Kernel 1: x = x_all @ W + b via split-bf16 MFMA, K-split over 4 waves.
// ---------------------------------------------------------------------------
__global__ __launch_bounds__(256) void xgemm_kernel(
    const float* __restrict__ xall,
    const __hip_bfloat16* __restrict__ Whi,
    const __hip_bfloat16* __restrict__ Wlo,
    const float* __restrict__ bias,
    float* __restrict__ x)
{
    __shared__ f32x4 red[3 * 512];   // 24 KB
    const int wave = threadIdx.x >> 6, lane = threadIdx.x & 63;
    const int lg = lane >> 4, lr = lane & 15;
    const int row0 = blockIdx.x * 16;
    const float* ap = xall + (size_t)(row0 + lr) * D_IN + wave * 288;

    f32x4 acc[8];
    #pragma unroll
    for (int ct = 0; ct < 8; ++ct) acc[ct] = {0.f, 0.f, 0.f, 0.f};

    const bf16x8* whb = reinterpret_cast<const bf16x8*>(Whi) + lane;
    const bf16x8* wlb = reinterpret_cast<const bf16x8*>(Wlo) + lane;

    for (int s = 0; s < 9; ++s) {
        const int gs = wave * 9 + s;
        const float* a8 = ap + s * 32 + lg * 8;
        float4 va = *reinterpret_cast<const float4*>(a8);
        float4 vb = *reinterpret_cast<const float4*>(a8 + 4);
        float v[8] = {va.x, va.y, va.z, va.w, vb.x, vb.y, vb.z, vb.w};
        bf16x8 ah, al;
        #pragma unroll
        for (int i = 0; i < 8; ++i) {
            short2 hl = splitf(v[i]);
            ah[i] = hl.x; al[i] = hl.y;
        }
        #pragma unroll
        for (int ct = 0; ct < 8; ++ct) {
            bf16x8 wh = whb[(size_t)(gs * 8 + ct) * 64];
            bf16x8 wl = wlb[(size_t)(gs * 8 + ct) * 64];
            acc[ct] = __builtin_amdgcn_mfma_f32_16x16x32_bf16(ah, wh, acc[ct], 0, 0, 0);
            acc[ct] = __builtin_amdgcn_mfma_f32_16x16x32_bf16(al, wh, acc[ct], 0, 0, 0);
            acc[ct] = __builtin_amdgcn_mfma_f32_16x16x32_bf16(ah, wl, acc[ct], 0, 0, 0);
        }
    }

    if (wave > 0) {
        #pragma unroll
        for (int ct = 0; ct < 8; ++ct)
            red[(wave - 1) * 512 + ct * 64 + lane] = acc[ct];
    }
    __syncthreads();
    if (wave == 0) {
        const int orow0 = row0 + lg * 4;
        #pragma unroll
        for (int ct = 0; ct < 8; ++ct) {
            f32x4 a = acc[ct];
            a += red[ct * 64 + lane];
            a += red[512 + ct * 64 + lane];
            a += red[1024 + ct * 64 + lane];
            float bj = bias[ct * 16 + lr];
            #pragma unroll
            for (int j = 0; j < 4; ++j)
                x[(size_t)(orow0 + j) * D_HID + ct * 16 + lr] = a[j] + bj;
        }
    }
}

// ---------------------------------------------------------------------------
// Kernel 2: retrieve via MFMA. Block = 128 threads: wave 0 -> U, wave 1 -> V.
// ---------------------------------------------------------------------------
__global__ __launch_bounds__(128) void retrieve_kernel(
    const float* __restrict__ x,
    const __hip_bfloat16* __restrict__ Pfhi,
    const __hip_bfloat16* __restrict__ Pflo,
    __hip_bfloat16* __restrict__ E)
{
    __shared__ float al[2][16 * 72];
    const int tid  = threadIdx.x;
    const int mat  = tid >> 6;
    const int lane = tid & 63;
    const int lg = lane >> 4, lr = lane & 15;
    const int row0 = blockIdx.x * 16;

    bf16x8 xh[4], xl[4];
    const float* xp = x + (size_t)(row0 + lr) * D_HID;
    #pragma unroll
    for (int s = 0; s < 4; ++s) {
        float4 va = *reinterpret_cast<const float4*>(xp + s * 32 + lg * 8);
        float4 vb = *reinterpret_cast<const float4*>(xp + s * 32 + lg * 8 + 4);
        float v[8] = {va.x, va.y, va.z, va.w, vb.x, vb.y, vb.z, vb.w};
        #pragma unroll
        for (int i = 0; i < 8; ++i) {
            short2 hl = splitf(v[i]);
            xh[s][i] = hl.x; xl[s][i] = hl.y;
        }
    }

    const bf16x8* bh = reinterpret_cast<const bf16x8*>(Pfhi) + (size_t)mat * 32 * 64 + lane;
    const bf16x8* bl = reinterpret_cast<const bf16x8*>(Pflo) + (size_t)mat * 32 * 64 + lane;

    f32x4 lacc[4];
    #pragma unroll
    for (int ct = 0; ct < 4; ++ct) lacc[ct] = {0.f, 0.f, 0.f, 0.f};
    #pragma unroll
    for (int ct = 0; ct < 4; ++ct) {
        #pragma unroll
        for (int s = 0; s < 4; ++s) {
            bf16x8 wh = bh[(s * 4 + ct) * 64];
            bf16x8 wl = bl[(s * 4 + ct) * 64];
            lacc[ct] = __builtin_amdgcn_mfma_f32_16x16x32_bf16(xh[s], wh, lacc[ct], 0, 0, 0);
            lacc[ct] = __builtin_amdgcn_mfma_f32_16x16x32_bf16(xl[s], wh, lacc[ct], 0, 0, 0);
            lacc[ct] = __builtin_amdgcn_mfma_f32_16x16x32_bf16(xh[s], wl, lacc[ct], 0, 0, 0);
        }
    }

    #pragma unroll
    for (int j = 0; j < 4; ++j) {
        float l0 = lacc[0][j], l1 = lacc[1][j], l2 = lacc[2][j], l3 = lacc[3][j];
        float mx = fmaxf(fmaxf(l0, l1), fmaxf(l2, l3));
        #pragma unroll
        for (int s = 1; s < 16; s <<= 1) mx = fmaxf(mx, __shfl_xor(mx, s));
        float p0 = fexp2(l0 - mx), p1 = fexp2(l1 - mx);
        float p2 = fexp2(l2 - mx), p3 = fexp2(l3 - mx);
        float sm = p0 + p1 + p2 + p3;
        #pragma unroll
        for (int s = 1; s < 16; s <<= 1) sm += __shfl_xor(sm, s);
        float inv = 1.0f / sm;
        float* ar = al[mat] + (lg * 4 + j) * 72;
        ar[lr]      = p0 * inv;
        ar[16 + lr] = p1 * inv;
        ar[32 + lr] = p2 * inv;
        ar[48 + lr] = p3 * inv;
    }
    __syncthreads();

    bf16x8 aah[2], aal[2];
    #pragma unroll
    for (int s2 = 0; s2 < 2; ++s2) {
        const float* ap = al[mat] + lr * 72 + s2 * 32 + lg * 8;
        float4 va = *reinterpret_cast<const float4*>(ap);
        float4 vb = *reinterpret_cast<const float4*>(ap + 4);
        float v[8] = {va.x, va.y, va.z, va.w, vb.x, vb.y, vb.z, vb.w};
        #pragma unroll
        for (int i = 0; i < 8; ++i) {
            short2 hl = splitf(v[i]);
            aah[s2][i] = hl.x; aal[s2][i] = hl.y;
        }
    }

    f32x4 eacc[8];
    #pragma unroll
    for (int ct2 = 0; ct2 < 8; ++ct2) eacc[ct2] = {0.f, 0.f, 0.f, 0.f};
    #pragma unroll
    for (int ct2 = 0; ct2 < 8; ++ct2) {
        #pragma unroll
        for (int s2 = 0; s2 < 2; ++s2) {
            bf16x8 wh = bh[(16 + s2 * 8 + ct2) * 64];
            bf16x8 wl = bl[(16 + s2 * 8 + ct2) * 64];
            eacc[ct2] = __builtin_amdgcn_mfma_f32_16x16x32_bf16(aah[s2], wh, eacc[ct2], 0, 0, 0);
            eacc[ct2] = __builtin_amdgcn_mfma_f32_16x16x32_bf16(aal[s2], wh, eacc[ct2], 0, 0, 0);
            eacc[ct2] = __builtin_amdgcn_mfma_f32_16x16x32_bf16(aah[s2], wl, eacc[ct2], 0, 0, 0);
        }
    }

    __hip_bfloat16* Er = E + ((size_t)mat * TOT_ROWS + row0) * D_HID;
    #pragma unroll
    for (int ct2 = 0; ct2 < 8; ++ct2) {
        #pragma unroll
        for (int j = 0; j < 4; ++j)
            Er[(size_t)(lg * 4 + j) * D_HID + ct2 * 16 + lr] =
                __float2bfloat16(eacc[ct2][j] * SCALE_E);
    }
}

// ---------------------------------------------------------------------------
// Kernel 3: pair LSE, K-split, 960 blocks x 512 threads (8 waves, rf=2).
// DEFER-MAX (T13): acc = s - m_old via MFMA C-fold. Per tile, compute the 8
// per-state maxes (fmax tree only); one wave-uniform __all(gmax <= 8) picks:
//  fast path (common): lrun += exp2(v0)+..+exp2(v3)   (no subs, no rescale)
//  slow path (rare):   full rescale with tp = max(tmax, 0)
// exp2 args <= 8 -> ps <= 1024, lrun <= 2^20: no overflow. exp2 is quarter-
// rate (8 cyc) so cutting exp2+sub count is the measured-VALU lever.
// Tile 0 runs absolute to establish (m, l).
// ---------------------------------------------------------------------------
__global__ __launch_bounds__(512) void pair_lse_kernel(
    const __hip_bfloat16* __restrict__ E,  // [2][6][2048][128], pre-scaled
    float* __restrict__ partial)           // [60][2048][2 halves][3]
{
    __shared__ __align__(16) unsigned char kbuf[2 * 16384];

    const int bid    = blockIdx.x;
    const int linear = (bid & 7) * 120 + (bid >> 3);  // 960 = 8 XCD x 120
    const int half = linear & 1;
    const int qt   = (linear >> 1) & 7;
    const int job  = linear >> 4;        // 0..59
    const int mat = job / 30;
    const int pr  = job % 30;
    const int m   = pr / 5;
    int k = pr % 5; k += (k >= m);

    const __hip_bfloat16* Qm = E + ((size_t)(mat * M_VIEWS + m)) * N_ROWS * D_HID;
    const __hip_bfloat16* Kk = E + ((size_t)(mat * M_VIEWS + k)) * N_ROWS * D_HID;

    const int tid  = threadIdx.x;
    const int wave = tid >> 6, lane = tid & 63;
    const int lr = lane & 15, lg = lane >> 4;

    const int qrow0 = qt * 256 + wave * 32;

    bf16x8 afrag[2][4];
    #pragma unroll
    for (int rf = 0; rf < 2; ++rf) {
        const __hip_bfloat16* qp = Qm + (size_t)(qrow0 + rf * 16 + lr) * D_HID;
        #pragma unroll
        for (int s = 0; s < 4; ++s)
            afrag[rf][s] = *reinterpret_cast<const bf16x8*>(qp + s * 32 + lg * 8);
    }

    // nmr = -runningmax (per lane, per row), lr4 = running sum, pos4
    f32x4 nmr[2], lr4[2], pos4[2];
    pos4[0] = {0.f, 0.f, 0.f, 0.f};
    pos4[1] = {0.f, 0.f, 0.f, 0.f};

    const int ptdiag = qt * 4 + (wave >> 1);
    const int ctd0   = (wave & 1) * 2;
    const int pt0    = half * 16;

    #define STAGE(pt, b)                                                        \
        {                                                                       \
            const char* base = (const char*)Kk + (size_t)(pt) * 16384;          \
            _Pragma("unroll")                                                   \
            for (int i = 0; i < 2; ++i) {                                       \
                int f = wave * 2 + i;                                           \
                int ct_ = f >> 2, s_ = f & 3;                                   \
                async16(base + (ct_ * 16 + lr) * 256 + s_ * 64 + lg * 16,       \
                        kbuf + (b) * 16384 + f * 1024);                         \
            }                                                                   \
        }

    STAGE(pt0, 0);
    __syncthreads();

    const unsigned char* kb0 = kbuf + lane * 16;

    // ---- tile 0: absolute domain, establishes nmr / lr4 ----
    {
        STAGE(pt0 + 1, 1);
        f32x4 acc[2][4];
        #pragma unroll
        for (int rf = 0; rf < 2; ++rf)
            #pragma unroll
            for (int ct = 0; ct < 4; ++ct) acc[rf][ct] = {0.f, 0.f, 0.f, 0.f};

        #pragma unroll
        for (int ct = 0; ct < 4; ++ct) {
            #pragma unroll
            for (int s = 0; s < 4; ++s) {
                bf16x8 bf = *reinterpret_cast<const bf16x8*>(kb0 + (ct * 4 + s) * 1024);
                acc[0][ct] = __builtin_amdgcn_mfma_f32_16x16x32_bf16(afrag[0][s], bf, acc[0][ct], 0, 0, 0);
                acc[1][ct] = __builtin_amdgcn_mfma_f32_16x16x32_bf16(afrag[1][s], bf, acc[1][ct], 0, 0, 0);
            }
        }

        const int dt = __builtin_amdgcn_readfirstlane((pt0 == ptdiag) ? 1 : 0);
        #pragma unroll
        for (int rf = 0; rf < 2; ++rf) {
            #pragma unroll
            for (int j = 0; j < 4; ++j) {
                float v0 = acc[rf][0][j], v1 = acc[rf][1][j];
                float v2 = acc[rf][2][j], v3 = acc[rf][3][j];
                if (dt) {
                    const int cd = ctd0 + rf;
                    const bool dl = (lr == lg * 4 + j);
                    float vd = (cd == 0) ? v0 : (cd == 1) ? v1 : (cd == 2) ? v2 : v3;
                    if (dl) {
                        pos4[rf][j] = vd;
                        float nv = -INFINITY;
                        if      (cd == 0) v0 = nv;
                        else if (cd == 1) v1 = nv;
                        else if (cd == 2) v2 = nv;
                        else              v3 = nv;
                    }
                }
                float tmax = fmaxf(fmaxf(v0, v1), fmaxf(v2, v3));
                nmr[rf][j] = -tmax;
                lr4[rf][j] = (fexp2(v0 - tmax) + fexp2(v1 - tmax))
                           + (fexp2(v2 - tmax) + fexp2(v3 - tmax));
            }
        }
        __syncthreads();
    }

    // ---- tiles 1..15: defer-max fast path ----
    for (int t = 1; t < 16; ++t) {
        const int pt = pt0 + t;
        if (t < 15) STAGE(pt + 1, (t + 1) & 1);

        const unsigned char* kb = kb0 + (t & 1) * 16384;
        f32x4 acc[2][4];
        #pragma unroll
        for (int ct = 0; ct < 4; ++ct) {
            bf16x8 bf0 = *reinterpret_cast<const bf16x8*>(kb + (ct * 4) * 1024);
            acc[0][ct] = __builtin_amdgcn_mfma_f32_16x16x32_bf16(afrag[0][0], bf0, nmr[0], 0, 0, 0);
            acc[1][ct] = __builtin_amdgcn_mfma_f32_16x16x32_bf16(afrag[1][0], bf0, nmr[1], 0, 0, 0);
            #pragma unroll
            for (int s = 1; s < 4; ++s) {
                bf16x8 bf = *reinterpret_cast<const bf16x8*>(kb + (ct * 4 + s) * 1024);
                acc[0][ct] = __builtin_amdgcn_mfma_f32_16x16x32_bf16(afrag[0][s], bf, acc[0][ct], 0, 0, 0);
                acc[1][ct] = __builtin_amdgcn_mfma_f32_16x16x32_bf16(afrag[1][s], bf, acc[1][ct], 0, 0, 0);
            }
        }

        // diag tile: capture pos, mask diag element (wave-uniform branch)
        const int dt = __builtin_amdgcn_readfirstlane((pt == ptdiag) ? 1 : 0);
        if (dt) {
            #pragma unroll
            for (int rf = 0; rf < 2; ++rf) {
                const int cd = ctd0 + rf;
                #pragma unroll
                for (int j = 0; j < 4; ++j) {
                    const bool dl = (lr == lg * 4 + j);
                    if (dl) {
                        float vd = (cd == 0) ? acc[rf][0][j] : (cd == 1) ? acc[rf][1][j]
                                 : (cd == 2) ? acc[rf][2][j] : acc[rf][3][j];
                        pos4[rf][j] = vd - nmr[rf][j];   // absolute s_d
                        if      (cd == 0) acc[rf][0][j] = -INFINITY;
                        else if (cd == 1) acc[rf][1][j] = -INFINITY;
                        else if (cd == 2) acc[rf][2][j] = -INFINITY;
                        else              acc[rf][3][j] = -INFINITY;
                    }
                }
            }
        }

        // per-state tile maxes (relative to m_old) + wave-wide growth check
        float tm[2][4];
        float gmax = -INFINITY;
        #pragma unroll
        for (int rf = 0; rf < 2; ++rf) {
            #pragma unroll
            for (int j = 0; j < 4; ++j) {
                float t0 = fmaxf(fmaxf(acc[rf][0][j], acc[rf][1][j]),
                                 fmaxf(acc[rf][2][j], acc[rf][3][j]));
                tm[rf][j] = t0;
                gmax = fmaxf(gmax, t0);
            }
        }

        if (__all(gmax <= 8.0f)) {
            // fast path: no rescale, args bounded by 8
            #pragma unroll
            for (int rf = 0; rf < 2; ++rf) {
                #pragma unroll
                for (int j = 0; j < 4; ++j) {
                    float ps = (fexp2(acc[rf][0][j]) + fexp2(acc[rf][1][j]))
                             + (fexp2(acc[rf][2][j]) + fexp2(acc[rf][3][j]));
                    lr4[rf][j] += ps;
                }
            }
        } else {
            // slow path: full rescale (ratchet by tp >= 0)
            #pragma unroll
            for (int rf = 0; rf < 2; ++rf) {
                #pragma unroll
                for (int j = 0; j < 4; ++j) {
                    float tp = fmaxf(tm[rf][j], 0.f);
                    float ps = (fexp2(acc[rf][0][j] - tp) + fexp2(acc[rf][1][j] - tp))
                             + (fexp2(acc[rf][2][j] - tp) + fexp2(acc[rf][3][j] - tp));
                    lr4[rf][j] = lr4[rf][j] * fexp2(-tp) + ps;
                    nmr[rf][j] -= tp;
                }
            }
        }
        __syncthreads();
    }

    // cross-lane merge over the 16 lr-lanes, then write per-row partials
    #pragma unroll
    for (int rf = 0; rf < 2; ++rf) {
        #pragma unroll
        for (int j = 0; j < 4; ++j) {
            float Mv = -nmr[rf][j], Lv = lr4[rf][j];
            #pragma unroll
            for (int s = 1; s < 16; s <<= 1) {
                float Mo = __shfl_xor(Mv, s);
                float Lo = __shfl_xor(Lv, s);
                float nm = fmaxf(Mv, Mo);
                Lv = Lv * fexp2(Mv - nm) + Lo * fexp2(Mo - nm);
                Mv = nm;
            }
            float P = pos4[rf][j];
            #pragma unroll
            for (int s = 1; s < 16; s <<= 1) P += __shfl_xor(P, s);
            if (lr == 0) {
                const int row = qrow0 + rf * 16 + lg * 4 + j;
                float* dst = partial + (((size_t)job * N_ROWS + row) * 2 + half) * 3;
                dst[0] = Mv; dst[1] = Lv; dst[2] = P;
            }
        }
    }
}

// ---------------------------------------------------------------------------
// Kernel 4: merge the two K-halves per row, sum (lse - pos) into out.
// ---------------------------------------------------------------------------
__global__ __launch_bounds__(256) void merge_kernel(
    const float* __restrict__ partial, float* __restrict__ out, float scale)
{
    __shared__ float wsum[4];
    const int r = blockIdx.x * 256 + threadIdx.x;   // 0 .. 60*2048-1
    const float* p = partial + (size_t)r * 6;
    float m0 = p[0], l0 = p[1], p0 = p[2];
    float m1 = p[3], l1 = p[4], p1 = p[5];
    float ms = fmaxf(m0, m1);
    float L  = l0 * fexp2(m0 - ms) + l1 * fexp2(m1 - ms);
    float c  = (ms + flog2(L)) - (p0 + p1);

    #pragma unroll
    for (int s = 1; s < 64; s <<= 1) c += __shfl_xor(c, s);
    const int wave = threadIdx.x >> 6, lane = threadIdx.x & 63;
    if (lane == 0) wsum[wave] = c;
    __syncthreads();
    if (threadIdx.x == 0)
        atomicAdd(out, (wsum[0] + wsum[1] + wsum[2] + wsum[3]) * scale);
}

// ---------------------------------------------------------------------------
extern "C" void kernel_launch(void* const* d_in, const int* in_sizes, int n_in,
                              void* d_out, int out_size, void* d_ws, size_t ws_size,
                              hipStream_t stream) {
    const float* xall = (const float*)d_in[0];
    const float* W    = (const float*)d_in[1];
    const float* b    = (const float*)d_in[2];
    const float* U    = (const float*)d_in[3];
    const float* V    = (const float*)d_in[4];
    float* out = (float*)d_out;

    char* ws = (char*)d_ws;
    float* x = (float*)ws;                                     // 6.29 MB
    __hip_bfloat16* E = (__hip_bfloat16*)(ws + (size_t)TOT_ROWS * D_HID * 4);
    __hip_bfloat16* Whi = E;                                   // overlay (pre-E)
    __hip_bfloat16* Wlo = E + 36 * 8 * 64 * 8;
    __hip_bfloat16* Pfhi = (__hip_bfloat16*)(ws + 2 * (size_t)TOT_ROWS * D_HID * 4);
    __hip_bfloat16* Pflo = Pfhi + 2 * 32 * 64 * 8;
    float* partial = (float*)(ws + 2 * (size_t)TOT_ROWS * D_HID * 4 + 262144);
    // partial: 60*2048*6 f32 = 2.95 MB; total ws use ~15.8 MB

    (void)hipMemsetAsync(d_out, 0, sizeof(float), stream);

    prep_w_kernel<<<36 * 8, 64, 0, stream>>>(W, Whi, Wlo);
    prep_p_kernel<<<64, 64, 0, stream>>>(U, V, Pfhi, Pflo);
    xgemm_kernel<<<TOT_ROWS / 16, 256, 0, stream>>>(xall, Whi, Wlo, b, x);
    retrieve_kernel<<<TOT_ROWS / 16, 128, 0, stream>>>(x, Pfhi, Pflo, E);

    pair_lse_kernel<<<960, 512, 0, stream>>>(E, partial);

    const float scale = 0.6931471805599453f / (2048.0f * 60.0f);
    merge_kernel<<<60 * 2048 / 256, 256, 0, stream>>>(partial, out, scale);
}

// Round 13
// 133.206 us; speedup vs baseline: 1.4281x; 1.4281x over previous
//
#include <hip/hip_runtime.h>
#include <hip/hip_bf16.h>

// Problem constants
#define M_VIEWS 6
#define N_ROWS  2048
#define D_IN    1152
#define D_HID   128
#define D_K     64
#define TOT_ROWS (M_VIEWS * N_ROWS)   // 12288
// E is pre-scaled by sqrt((1/tau) * log2(e)) so E'.E' = (s/tau)*log2(e):
// pair-LSE softmax runs in exp2/log2 domain with no per-element muls.
#define SCALE_E 1.6986436f
#define LOG2E   1.4426950408889634f

typedef short bf16x8 __attribute__((ext_vector_type(8)));
typedef float f32x4  __attribute__((ext_vector_type(4)));

typedef __attribute__((address_space(1))) const void gvoid_t;
typedef __attribute__((address_space(3))) void svoid_t;

__device__ inline void async16(const void* g, void* l) {
    __builtin_amdgcn_global_load_lds((gvoid_t*)g, (svoid_t*)l, 16, 0, 0);
}

#if __has_builtin(__builtin_amdgcn_exp2f)
__device__ inline float fexp2(float x) { return __builtin_amdgcn_exp2f(x); }
#else
__device__ inline float fexp2(float x) { return exp2f(x); }
#endif
#if __has_builtin(__builtin_amdgcn_logf)
__device__ inline float flog2(float x) { return __builtin_amdgcn_logf(x); }
#else
__device__ inline float flog2(float x) { return log2f(x); }
#endif

// split f32 -> bf16 hi (x) + bf16 lo residual (y), returned by value
__device__ inline short2 splitf(float v) {
    __hip_bfloat16 hb = __float2bfloat16(v);
    float rem = v - __bfloat162float(hb);
    __hip_bfloat16 lb = __float2bfloat16(rem);
    short2 r;
    r.x = *reinterpret_cast<const short*>(&hb);
    r.y = *reinterpret_cast<const short*>(&lb);
    return r;
}

__device__ inline short bf16of(float v) {
    __hip_bfloat16 hb = __float2bfloat16(v);
    return *reinterpret_cast<const short*>(&hb);
}

// ---------------------------------------------------------------------------
// Kernel 0a: W as bf16 MFMA B-fragments (single precision term — quantization
// error averages down by sqrt(K=1152) in the dot; negligible vs threshold).
// ---------------------------------------------------------------------------
__global__ __launch_bounds__(64) void prep_w_kernel(
    const float* __restrict__ W, __hip_bfloat16* __restrict__ Whi)
{
    const int s    = blockIdx.x >> 3;   // 0..35
    const int ct   = blockIdx.x & 7;    // 0..7
    const int lane = threadIdx.x;
    const int lg = lane >> 4, lr = lane & 15;
    bf16x8 hi;
    #pragma unroll
    for (int i = 0; i < 8; ++i)
        hi[i] = bf16of(W[(size_t)(s * 32 + lg * 8 + i) * D_HID + ct * 16 + lr]);
    size_t off = ((size_t)(s * 8 + ct) * 64 + lane) * 8;
    *reinterpret_cast<bf16x8*>(Whi + off) = hi;
}

// ---------------------------------------------------------------------------
// Kernel 0b: U/V as MFMA B-fragments, hi/lo split (3-term kept here).
// ---------------------------------------------------------------------------
__global__ __launch_bounds__(64) void prep_p_kernel(
    const float* __restrict__ U, const float* __restrict__ V,
    __hip_bfloat16* __restrict__ Pfhi, __hip_bfloat16* __restrict__ Pflo)
{
    const int blk = blockIdx.x;       // 0..63
    const int mat = blk >> 5, f = blk & 31;
    const float* P = mat ? V : U;
    const int lane = threadIdx.x, lg = lane >> 4, lr = lane & 15;
    bf16x8 hi, lo;
    #pragma unroll
    for (int i = 0; i < 8; ++i) {
        float w;
        if (f < 16) {
            int s = f >> 2, ct = f & 3;
            w = P[(size_t)(s * 32 + lg * 8 + i) * D_K + ct * 16 + lr] * LOG2E;
        } else {
            int g = f - 16, s2 = g >> 3, ct2 = g & 7;
            w = P[(size_t)(ct2 * 16 + lr) * D_K + s2 * 32 + lg * 8 + i];
        }
        short2 hl = splitf(w);
        hi[i] = hl.x; lo[i] = hl.y;
    }
    size_t off = ((size_t)(mat * 32 + f) * 64 + lane) * 8;
    *reinterpret_cast<bf16x8*>(Pfhi + off) = hi;
    *reinterpret_cast<bf16x8*>(Pflo + off) = lo;
}

// ---------------------------------------------------------------------------
// Kernel 1+2 FUSED: x = x_all@W + b (bf16 MFMA, K-split over 4 waves), then
// retrieve E = SCALE_E * (P @ softmax(x@P)) for both mats — x never touches
// global memory (LDS tile, pad-132 stride). Block = 16 rows, 256 threads.
// ---------------------------------------------------------------------------
__global__ __launch_bounds__(256) void xretrieve_kernel(
    const float* __restrict__ xall,
    const __hip_bfloat16* __restrict__ Whi,
    const float* __restrict__ bias,
    const __hip_bfloat16* __restrict__ Pfhi,
    const __hip_bfloat16* __restrict__ Pflo,
    __hip_bfloat16* __restrict__ E)
{
    __shared__ __align__(16) char smem[24576];   // red (24576) -> xs+al
    f32x4* red = reinterpret_cast<f32x4*>(smem);           // 3*512 f32x4
    float* xs  = reinterpret_cast<float*>(smem);           // 16*132 f32 = 8448B
    float* alb = reinterpret_cast<float*>(smem + 8448);    // 2*16*72 f32 = 9216B

    const int wave = threadIdx.x >> 6, lane = threadIdx.x & 63;
    const int lg = lane >> 4, lr = lane & 15;
    const int row0 = blockIdx.x * 16;

    // ---- phase 1: xgemm (single-term bf16) ----
    const float* ap = xall + (size_t)(row0 + lr) * D_IN + wave * 288;
    f32x4 acc[8];
    #pragma unroll
    for (int ct = 0; ct < 8; ++ct) acc[ct] = {0.f, 0.f, 0.f, 0.f};

    const bf16x8* whb = reinterpret_cast<const bf16x8*>(Whi) + lane;
    for (int s = 0; s < 9; ++s) {
        const int gs = wave * 9 + s;
        const float* a8 = ap + s * 32 + lg * 8;
        float4 va = *reinterpret_cast<const float4*>(a8);
        float4 vb = *reinterpret_cast<const float4*>(a8 + 4);
        bf16x8 ah;
        ah[0] = bf16of(va.x); ah[1] = bf16of(va.y);
        ah[2] = bf16of(va.z); ah[3] = bf16of(va.w);
        ah[4] = bf16of(vb.x); ah[5] = bf16of(vb.y);
        ah[6] = bf16of(vb.z); ah[7] = bf16of(vb.w);
        #pragma unroll
        for (int ct = 0; ct < 8; ++ct) {
            bf16x8 wh = whb[(size_t)(gs * 8 + ct) * 64];
            acc[ct] = __builtin_amdgcn_mfma_f32_16x16x32_bf16(ah, wh, acc[ct], 0, 0, 0);
        }
    }

    if (wave > 0) {
        #pragma unroll
        for (int ct = 0; ct < 8; ++ct)
            red[(wave - 1) * 512 + ct * 64 + lane] = acc[ct];
    }
    __syncthreads();
    if (wave == 0) {
        // reduce; write x-tile to LDS (row stride 132 f32: 2-way banks, free)
        f32x4 xv[8];
        #pragma unroll
        for (int ct = 0; ct < 8; ++ct) {
            f32x4 a = acc[ct];
            a += red[ct * 64 + lane];
            a += red[512 + ct * 64 + lane];
            a += red[1024 + ct * 64 + lane];
            float bj = bias[ct * 16 + lr];
            #pragma unroll
            for (int j = 0; j < 4; ++j) xv[ct][j] = a[j] + bj;
        }
        __syncthreads();   // red reads done everywhere before overwrite
        #pragma unroll
        for (int ct = 0; ct < 8; ++ct)
            #pragma unroll
            for (int j = 0; j < 4; ++j)
                xs[(lg * 4 + j) * 132 + ct * 16 + lr] = xv[ct][j];
    } else {
        __syncthreads();   // matching barrier
    }
    __syncthreads();       // xs visible to all

    // ---- phase 2: retrieve (waves 0,1 = mats U,V) ----
    const int mat = wave;
    if (wave < 2) {
        bf16x8 xh[4], xl[4];
        #pragma unroll
        for (int s = 0; s < 4; ++s) {
            const float* xp = xs + lr * 132 + s * 32 + lg * 8;
            float4 va = *reinterpret_cast<const float4*>(xp);
            float4 vb = *reinterpret_cast<const float4*>(xp + 4);
            float v[8] = {va.x, va.y, va.z, va.w, vb.x, vb.y, vb.z, vb.w};
            #pragma unroll
            for (int i = 0; i < 8; ++i) {
                short2 hl = splitf(v[i]);
                xh[s][i] = hl.x; xl[s][i] = hl.y;
            }
        }

        const bf16x8* bh = reinterpret_cast<const bf16x8*>(Pfhi) + (size_t)mat * 32 * 64 + lane;
        const bf16x8* bl = reinterpret_cast<const bf16x8*>(Pflo) + (size_t)mat * 32 * 64 + lane;

        f32x4 lacc[4];
        #pragma unroll
        for (int ct = 0; ct < 4; ++ct) lacc[ct] = {0.f, 0.f, 0.f, 0.f};
        #pragma unroll
        for (int ct = 0; ct < 4; ++ct) {
            #pragma unroll
            for (int s = 0; s < 4; ++s) {
                bf16x8 wh = bh[(s * 4 + ct) * 64];
                bf16x8 wl = bl[(s * 4 + ct) * 64];
                lacc[ct] = __builtin_amdgcn_mfma_f32_16x16x32_bf16(xh[s], wh, lacc[ct], 0, 0, 0);
                lacc[ct] = __builtin_amdgcn_mfma_f32_16x16x32_bf16(xl[s], wh, lacc[ct], 0, 0, 0);
                lacc[ct] = __builtin_amdgcn_mfma_f32_16x16x32_bf16(xh[s], wl, lacc[ct], 0, 0, 0);
            }
        }

        float* al = alb + mat * (16 * 72);
        #pragma unroll
        for (int j = 0; j < 4; ++j) {
            float l0 = lacc[0][j], l1 = lacc[1][j], l2 = lacc[2][j], l3 = lacc[3][j];
            float mx = fmaxf(fmaxf(l0, l1), fmaxf(l2, l3));
            #pragma unroll
            for (int s = 1; s < 16; s <<= 1) mx = fmaxf(mx, __shfl_xor(mx, s));
            float p0 = fexp2(l0 - mx), p1 = fexp2(l1 - mx);
            float p2 = fexp2(l2 - mx), p3 = fexp2(l3 - mx);
            float sm = p0 + p1 + p2 + p3;
            #pragma unroll
            for (int s = 1; s < 16; s <<= 1) sm += __shfl_xor(sm, s);
            float inv = 1.0f / sm;
            float* ar = al + (lg * 4 + j) * 72;
            ar[lr]      = p0 * inv;
            ar[16 + lr] = p1 * inv;
            ar[32 + lr] = p2 * inv;
            ar[48 + lr] = p3 * inv;
        }
    }
    __syncthreads();   // al visible

    if (wave < 2) {
        const float* al = alb + mat * (16 * 72);
        const bf16x8* bh = reinterpret_cast<const bf16x8*>(Pfhi) + (size_t)mat * 32 * 64 + lane;
        const bf16x8* bl = reinterpret_cast<const bf16x8*>(Pflo) + (size_t)mat * 32 * 64 + lane;

        bf16x8 aah[2], aal[2];
        #pragma unroll
        for (int s2 = 0; s2 < 2; ++s2) {
            const float* ap2 = al + lr * 72 + s2 * 32 + lg * 8;
            float4 va = *reinterpret_cast<const float4*>(ap2);
            float4 vb = *reinterpret_cast<const float4*>(ap2 + 4);
            float v[8] = {va.x, va.y, va.z, va.w, vb.x, vb.y, vb.z, vb.w};
            #pragma unroll
            for (int i = 0; i < 8; ++i) {
                short2 hl = splitf(v[i]);
                aah[s2][i] = hl.x; aal[s2][i] = hl.y;
            }
        }

        f32x4 eacc[8];
        #pragma unroll
        for (int ct2 = 0; ct2 < 8; ++ct2) eacc[ct2] = {0.f, 0.f, 0.f, 0.f};
        #pragma unroll
        for (int ct2 = 0; ct2 < 8; ++ct2) {
            #pragma unroll
            for (int s2 = 0; s2 < 2; ++s2) {
                bf16x8 wh = bh[(16 + s2 * 8 + ct2) * 64];
                bf16x8 wl = bl[(16 + s2 * 8 + ct2) * 64];
                eacc[ct2] = __builtin_amdgcn_mfma_f32_16x16x32_bf16(aah[s2], wh, eacc[ct2], 0, 0, 0);
                eacc[ct2] = __builtin_amdgcn_mfma_f32_16x16x32_bf16(aal[s2], wh, eacc[ct2], 0, 0, 0);
                eacc[ct2] = __builtin_amdgcn_mfma_f32_16x16x32_bf16(aah[s2], wl, eacc[ct2], 0, 0, 0);
            }
        }

        __hip_bfloat16* Er = E + ((size_t)mat * TOT_ROWS + row0) * D_HID;
        #pragma unroll
        for (int ct2 = 0; ct2 < 8; ++ct2) {
            #pragma unroll
            for (int j = 0; j < 4; ++j)
                Er[(size_t)(lg * 4 + j) * D_HID + ct2 * 16 + lr] =
                    __float2bfloat16(eacc[ct2][j] * SCALE_E);
        }
    }
}

// ---------------------------------------------------------------------------
// Kernel 3: pair LSE, K-SPLIT (R9 version — measured best, 102.5 us).
// 960 blocks x 512 threads (8 waves, rf=2), per-tile-max online LSE.
// ---------------------------------------------------------------------------
__global__ __launch_bounds__(512) void pair_lse_kernel(
    const __hip_bfloat16* __restrict__ E,  // [2][6][2048][128], pre-scaled
    float* __restrict__ partial)           // [60][2048][2 halves][3]
{
    __shared__ __align__(16) unsigned char kbuf[2 * 16384];

    const int bid    = blockIdx.x;
    const int linear = (bid & 7) * 120 + (bid >> 3);  // 960 = 8 XCD x 120
    const int half = linear & 1;
    const int qt   = (linear >> 1) & 7;
    const int job  = linear >> 4;        // 0..59
    const int mat = job / 30;
    const int pr  = job % 30;
    const int m   = pr / 5;
    int k = pr % 5; k += (k >= m);

    const __hip_bfloat16* Qm = E + ((size_t)(mat * M_VIEWS + m)) * N_ROWS * D_HID;
    const __hip_bfloat16* Kk = E + ((size_t)(mat * M_VIEWS + k)) * N_ROWS * D_HID;

    const int tid  = threadIdx.x;
    const int wave = tid >> 6, lane = tid & 63;
    const int lr = lane & 15, lg = lane >> 4;

    const int qrow0 = qt * 256 + wave * 32;

    bf16x8 afrag[2][4];
    #pragma unroll
    for (int rf = 0; rf < 2; ++rf) {
        const __hip_bfloat16* qp = Qm + (size_t)(qrow0 + rf * 16 + lr) * D_HID;
        #pragma unroll
        for (int s = 0; s < 4; ++s)
            afrag[rf][s] = *reinterpret_cast<const bf16x8*>(qp + s * 32 + lg * 8);
    }

    float mrun[2][4], lrun[2][4], pos[2][4];
    #pragma unroll
    for (int rf = 0; rf < 2; ++rf)
        #pragma unroll
        for (int j = 0; j < 4; ++j) {
            mrun[rf][j] = -1e30f; lrun[rf][j] = 0.f; pos[rf][j] = 0.f;
        }

    const int ptdiag = qt * 4 + (wave >> 1);
    const int ctd0   = (wave & 1) * 2;
    const int pt0    = half * 16;

    #define STAGE(pt, b)                                                        \
        {                                                                       \
            const char* base = (const char*)Kk + (size_t)(pt) * 16384;          \
            _Pragma("unroll")                                                   \
            for (int i = 0; i < 2; ++i) {                                       \
                int f = wave * 2 + i;                                           \
                int ct_ = f >> 2, s_ = f & 3;                                   \
                async16(base + (ct_ * 16 + lr) * 256 + s_ * 64 + lg * 16,       \
                        kbuf + (b) * 16384 + f * 1024);                         \
            }                                                                   \
        }

    STAGE(pt0, 0);
    __syncthreads();

    const unsigned char* kb0 = kbuf + lane * 16;
    for (int t = 0; t < 16; ++t) {
        const int pt = pt0 + t;
        if (t < 15) STAGE(pt + 1, (t + 1) & 1);

        const unsigned char* kb = kb0 + (t & 1) * 16384;
        f32x4 acc[2][4];
        #pragma unroll
        for (int rf = 0; rf < 2; ++rf)
            #pragma unroll
            for (int ct = 0; ct < 4; ++ct) acc[rf][ct] = {0.f, 0.f, 0.f, 0.f};

        #pragma unroll
        for (int ct = 0; ct < 4; ++ct) {
            #pragma unroll
            for (int s = 0; s < 4; ++s) {
                bf16x8 bf = *reinterpret_cast<const bf16x8*>(kb + (ct * 4 + s) * 1024);
                acc[0][ct] = __builtin_amdgcn_mfma_f32_16x16x32_bf16(afrag[0][s], bf, acc[0][ct], 0, 0, 0);
                acc[1][ct] = __builtin_amdgcn_mfma_f32_16x16x32_bf16(afrag[1][s], bf, acc[1][ct], 0, 0, 0);
            }
        }

        const bool dtile = (pt == ptdiag);
        #pragma unroll
        for (int rf = 0; rf < 2; ++rf) {
            #pragma unroll
            for (int j = 0; j < 4; ++j) {
                float v0 = acc[rf][0][j], v1 = acc[rf][1][j];
                float v2 = acc[rf][2][j], v3 = acc[rf][3][j];
                if (dtile) {
                    const int cd = ctd0 + rf;     // wave-uniform
                    const bool dl = (lr == lg * 4 + j);
                    float vd = (cd == 0) ? v0 : (cd == 1) ? v1 : (cd == 2) ? v2 : v3;
                    if (dl) {
                        pos[rf][j] = vd;
                        float nv = -INFINITY;
                        if      (cd == 0) v0 = nv;
                        else if (cd == 1) v1 = nv;
                        else if (cd == 2) v2 = nv;
                        else              v3 = nv;
                    }
                }
                float tmax = fmaxf(fmaxf(v0, v1), fmaxf(v2, v3));
                float nm = fmaxf(mrun[rf][j], tmax);
                float ps = fexp2(v0 - nm) + fexp2(v1 - nm)
                         + fexp2(v2 - nm) + fexp2(v3 - nm);
                lrun[rf][j] = lrun[rf][j] * fexp2(mrun[rf][j] - nm) + ps;
                mrun[rf][j] = nm;
            }
        }
        __syncthreads();
    }

    #pragma unroll
    for (int rf = 0; rf < 2; ++rf) {
        #pragma unroll
        for (int j = 0; j < 4; ++j) {
            float Mv = mrun[rf][j], Lv = lrun[rf][j];
            #pragma unroll
            for (int s = 1; s < 16; s <<= 1) {
                float Mo = __shfl_xor(Mv, s);
                float Lo = __shfl_xor(Lv, s);
                float nm = fmaxf(Mv, Mo);
                Lv = Lv * fexp2(Mv - nm) + Lo * fexp2(Mo - nm);
                Mv = nm;
            }
            float P = pos[rf][j];
            #pragma unroll
            for (int s = 1; s < 16; s <<= 1) P += __shfl_xor(P, s);
            if (lr == 0) {
                const int row = qrow0 + rf * 16 + lg * 4 + j;
                float* dst = partial + (((size_t)job * N_ROWS + row) * 2 + half) * 3;
                dst[0] = Mv; dst[1] = Lv; dst[2] = P;
            }
        }
    }
}

// ---------------------------------------------------------------------------
// Kernel 4: merge the two K-halves per row, sum (lse - pos) into out.
// ---------------------------------------------------------------------------
__global__ __launch_bounds__(256) void merge_kernel(
    const float* __restrict__ partial, float* __restrict__ out, float scale)
{
    __shared__ float wsum[4];
    const int r = blockIdx.x * 256 + threadIdx.x;   // 0 .. 60*2048-1
    const float* p = partial + (size_t)r * 6;
    float m0 = p[0], l0 = p[1], p0 = p[2];
    float m1 = p[3], l1 = p[4], p1 = p[5];
    float ms = fmaxf(m0, m1);
    float L  = l0 * fexp2(m0 - ms) + l1 * fexp2(m1 - ms);
    float c  = (ms + flog2(L)) - (p0 + p1);

    #pragma unroll
    for (int s = 1; s < 64; s <<= 1) c += __shfl_xor(c, s);
    const int wave = threadIdx.x >> 6, lane = threadIdx.x & 63;
    if (lane == 0) wsum[wave] = c;
    __syncthreads();
    if (threadIdx.x == 0)
        atomicAdd(out, (wsum[0] + wsum[1] + wsum[2] + wsum[3]) * scale);
}

// ---------------------------------------------------------------------------
extern "C" void kernel_launch(void* const* d_in, const int* in_sizes, int n_in,
                              void* d_out, int out_size, void* d_ws, size_t ws_size,
                              hipStream_t stream) {
    const float* xall = (const float*)d_in[0];
    const float* W    = (const float*)d_in[1];
    const float* b    = (const float*)d_in[2];
    const float* U    = (const float*)d_in[3];
    const float* V    = (const float*)d_in[4];
    float* out = (float*)d_out;

    char* ws = (char*)d_ws;
    __hip_bfloat16* E   = (__hip_bfloat16*)ws;                 // 6.29 MB
    __hip_bfloat16* Whi = E + 2 * (size_t)TOT_ROWS * D_HID;    // 294,912 B
    __hip_bfloat16* Pfhi = Whi + 36 * 8 * 64 * 8;              // 64 KB
    __hip_bfloat16* Pflo = Pfhi + 2 * 32 * 64 * 8;             // 64 KB
    float* partial = (float*)(Pflo + 2 * 32 * 64 * 8);         // 2.95 MB

    (void)hipMemsetAsync(d_out, 0, sizeof(float), stream);

    prep_w_kernel<<<36 * 8, 64, 0, stream>>>(W, Whi);
    prep_p_kernel<<<64, 64, 0, stream>>>(U, V, Pfhi, Pflo);
    xretrieve_kernel<<<TOT_ROWS / 16, 256, 0, stream>>>(xall, Whi, b, Pfhi, Pflo, E);

    pair_lse_kernel<<<960, 512, 0, stream>>>(E, partial);

    const float scale = 0.6931471805599453f / (2048.0f * 60.0f);
    merge_kernel<<<60 * 2048 / 256, 256, 0, stream>>>(partial, out, scale);
}